// Round 1
// baseline (427.192 us; speedup 1.0000x reference)
//
#include <hip/hip_runtime.h>

#define HH 128
#define WW 128
#define HWSZ (HH * WW)   // 16384
#define CC 64
#define BB 2

// ---------------------------------------------------------------------------
// Kernel 1: K/Q/V = relu(W @ x) over channels.
// Thread layout: lane (tid&63) = pixel within block's 64-pixel chunk,
// og (tid>>6) = which 16 output channels. Weight reads are wave-uniform ->
// scalar loads. x loads coalesced (lane-consecutive hw).
// ---------------------------------------------------------------------------
__global__ __launch_bounds__(256, 1) void kqv_kernel(
    const float* __restrict__ x,  const float* __restrict__ Wk,
    const float* __restrict__ Wq, const float* __restrict__ Wv,
    float* __restrict__ Ko, float* __restrict__ Qo, float* __restrict__ Vo)
{
    const int lane = threadIdx.x & 63;
    const int og   = threadIdx.x >> 6;        // 0..3
    const int p    = blockIdx.x * 64 + lane;  // 0..32767
    const int b    = p >> 14;
    const int hw   = p & 16383;
    const float* xp = x + (size_t)b * CC * HWSZ + hw;

    float aK[16], aQ[16], aV[16];
#pragma unroll
    for (int i = 0; i < 16; ++i) { aK[i] = 0.f; aQ[i] = 0.f; aV[i] = 0.f; }

    const float* wkp = Wk + og * 16 * CC;
    const float* wqp = Wq + og * 16 * CC;
    const float* wvp = Wv + og * 16 * CC;

    for (int c = 0; c < CC; ++c) {
        const float xv = xp[(size_t)c * HWSZ];
#pragma unroll
        for (int i = 0; i < 16; ++i) {
            aK[i] = fmaf(wkp[i * CC + c], xv, aK[i]);
            aQ[i] = fmaf(wqp[i * CC + c], xv, aQ[i]);
            aV[i] = fmaf(wvp[i * CC + c], xv, aV[i]);
        }
    }

    float* kp = Ko + (size_t)b * CC * HWSZ + (size_t)(og * 16) * HWSZ + hw;
    float* qp = Qo + (size_t)b * CC * HWSZ + (size_t)(og * 16) * HWSZ + hw;
    float* vp = Vo + (size_t)b * CC * HWSZ + (size_t)(og * 16) * HWSZ + hw;
#pragma unroll
    for (int i = 0; i < 16; ++i) {
        kp[(size_t)i * HWSZ] = fmaxf(aK[i], 0.f);
        qp[(size_t)i * HWSZ] = fmaxf(aQ[i], 0.f);
        vp[(size_t)i * HWSZ] = fmaxf(aV[i], 0.f);
    }
}

// ---------------------------------------------------------------------------
// Kernel 2: fused dilated 7x7 attention + softmax(49) + V-aggregate +
// Wt 1x1 conv + residual. One block per output row (b,h); thread = pixel w.
// Per channel: stage 7 clamped extended K(or V) rows [140 wide] in LDS, then
// each lane does 49 stride-2 LDS reads (ds_read2-mergeable) + 49 FMAs.
// Scores live in 49 regs; final Wt accumulation in 64 regs (static unroll,
// wave-uniform weight -> scalar loads).
// ---------------------------------------------------------------------------
__global__ __launch_bounds__(128, 1) void attn_kernel(
    const float* __restrict__ Kb, const float* __restrict__ Qb,
    const float* __restrict__ Vb, const float* __restrict__ x,
    const float* __restrict__ Wt, float* __restrict__ out)
{
    __shared__ float st[7][144];

    const int w = threadIdx.x;          // 0..127
    const int h = blockIdx.x & 127;
    const int b = blockIdx.x >> 7;
    const size_t plane = (size_t)HWSZ;

    const float* Kbase = Kb + (size_t)b * CC * plane;
    const float* Qbase = Qb + (size_t)b * CC * plane;
    const float* Vbase = Vb + (size_t)b * CC * plane;

    int hn[7];
#pragma unroll
    for (int i = 0; i < 7; ++i) {
        int hh = h + 2 * i - 6;
        hn[i] = hh < 0 ? 0 : (hh > HH - 1 ? HH - 1 : hh);
    }

    float sc[49];
#pragma unroll
    for (int k = 0; k < 49; ++k) sc[k] = 0.f;

    // ---- Pass A: scores over channels ----
    for (int c = 0; c < CC; ++c) {
        __syncthreads();
#pragma unroll
        for (int i = 0; i < 7; ++i) {
            const float* krow = Kbase + (size_t)c * plane + hn[i] * WW;
            for (int t = w; t < 140; t += 128) {
                int wc = t - 6;
                wc = wc < 0 ? 0 : (wc > WW - 1 ? WW - 1 : wc);
                st[i][t] = krow[wc];
            }
        }
        __syncthreads();
        const float qv = Qbase[(size_t)c * plane + h * WW + w];
#pragma unroll
        for (int i = 0; i < 7; ++i)
#pragma unroll
            for (int j = 0; j < 7; ++j)
                sc[i * 7 + j] = fmaf(st[i][w + 2 * j], qv, sc[i * 7 + j]);
    }

    // ---- softmax over the 49 neighbors (in registers) ----
    float m = sc[0];
#pragma unroll
    for (int k = 1; k < 49; ++k) m = fmaxf(m, sc[k]);
    float s = 0.f;
#pragma unroll
    for (int k = 0; k < 49; ++k) { sc[k] = __expf(sc[k] - m); s += sc[k]; }
    const float inv = 1.f / s;
#pragma unroll
    for (int k = 0; k < 49; ++k) sc[k] *= inv;

    // ---- Pass B: V aggregate + fused Wt conv + residual ----
    float fin[64];
    const float* xpix = x + (size_t)b * CC * plane + h * WW + w;
#pragma unroll
    for (int o = 0; o < 64; ++o) fin[o] = xpix[(size_t)o * plane];

    for (int c = 0; c < CC; ++c) {
        __syncthreads();
#pragma unroll
        for (int i = 0; i < 7; ++i) {
            const float* vrow = Vbase + (size_t)c * plane + hn[i] * WW;
            for (int t = w; t < 140; t += 128) {
                int wc = t - 6;
                wc = wc < 0 ? 0 : (wc > WW - 1 ? WW - 1 : wc);
                st[i][t] = vrow[wc];
            }
        }
        __syncthreads();
        float oc = 0.f;
#pragma unroll
        for (int i = 0; i < 7; ++i)
#pragma unroll
            for (int j = 0; j < 7; ++j)
                oc = fmaf(st[i][w + 2 * j], sc[i * 7 + j], oc);
#pragma unroll
        for (int o = 0; o < 64; ++o)
            fin[o] = fmaf(Wt[o * CC + c], oc, fin[o]);
    }

    float* op = out + (size_t)b * CC * plane + h * WW + w;
#pragma unroll
    for (int o = 0; o < 64; ++o) op[(size_t)o * plane] = fin[o];
}

// ---------------------------------------------------------------------------
extern "C" void kernel_launch(void* const* d_in, const int* in_sizes, int n_in,
                              void* d_out, int out_size, void* d_ws, size_t ws_size,
                              hipStream_t stream)
{
    const float* x  = (const float*)d_in[0];
    const float* Wk = (const float*)d_in[1];
    const float* Wq = (const float*)d_in[2];
    const float* Wv = (const float*)d_in[3];
    const float* Wt = (const float*)d_in[4];
    float* out = (float*)d_out;

    const size_t tensor_elems = (size_t)BB * CC * HWSZ;  // 2,097,152
    float* Kb = (float*)d_ws;
    float* Qb = Kb + tensor_elems;
    float* Vb = Qb + tensor_elems;

    hipLaunchKernelGGL(kqv_kernel, dim3(32768 / 64), dim3(256), 0, stream,
                       x, Wk, Wq, Wv, Kb, Qb, Vb);
    hipLaunchKernelGGL(attn_kernel, dim3(BB * HH), dim3(128), 0, stream,
                       Kb, Qb, Vb, x, Wt, out);
}

// Round 3
// 138.534 us; speedup vs baseline: 3.0837x; 3.0837x over previous
//
#include <hip/hip_runtime.h>

#define HH 128
#define WW 128
#define HWSZ (HH * WW)   // 16384
#define CC 64
#define BB 2
#define KK 7
#define K2 49

__device__ __forceinline__ int clampi(int v, int lo, int hi) {
    return v < lo ? lo : (v > hi ? hi : v);
}

// ---------------------------------------------------------------------------
// K1: K/Q/V = relu(W @ x). Grid: og(0..7) x 128 pixel-blocks, 256 thr.
// Each thread: 1 pixel, 8 output channels per matrix (24 accumulators).
// ---------------------------------------------------------------------------
__global__ __launch_bounds__(256) void kqv_kernel(
    const float* __restrict__ x,  const float* __restrict__ Wk,
    const float* __restrict__ Wq, const float* __restrict__ Wv,
    float* __restrict__ Ko, float* __restrict__ Qo, float* __restrict__ Vo)
{
    const int pb = blockIdx.x & 127;
    const int og = blockIdx.x >> 7;            // 0..7
    const int p  = pb * 256 + threadIdx.x;     // 0..32767
    const int b  = p >> 14;
    const int hw = p & 16383;
    const int o0 = og * 8;
    const float* xp = x + (size_t)b * CC * HWSZ + hw;

    float aK[8], aQ[8], aV[8];
#pragma unroll
    for (int i = 0; i < 8; ++i) { aK[i] = 0.f; aQ[i] = 0.f; aV[i] = 0.f; }

#pragma unroll 4
    for (int c = 0; c < CC; ++c) {
        const float xv = xp[(size_t)c * HWSZ];
#pragma unroll
        for (int i = 0; i < 8; ++i) {
            aK[i] = fmaf(Wk[(o0 + i) * CC + c], xv, aK[i]);
            aQ[i] = fmaf(Wq[(o0 + i) * CC + c], xv, aQ[i]);
            aV[i] = fmaf(Wv[(o0 + i) * CC + c], xv, aV[i]);
        }
    }

    const size_t obase = (size_t)b * CC * HWSZ + (size_t)o0 * HWSZ + hw;
#pragma unroll
    for (int i = 0; i < 8; ++i) {
        Ko[obase + (size_t)i * HWSZ] = fmaxf(aK[i], 0.f);
        Qo[obase + (size_t)i * HWSZ] = fmaxf(aQ[i], 0.f);
        Vo[obase + (size_t)i * HWSZ] = fmaxf(aV[i], 0.f);
    }
}

// ---------------------------------------------------------------------------
// K2: scores A[b][k=i*7+j][h][w] = sum_c K[b,c,hn(i),wn(j)] * Q[b,c,h,w].
// Grid: (b,h,i) = 1792 blocks x 128 thr. Each block owns neighbor-row i
// (7 j outputs), loops all 64 channels in chunks of 8 (one staged row each).
// ---------------------------------------------------------------------------
__global__ __launch_bounds__(128) void score_kernel(
    const float* __restrict__ Kb, const float* __restrict__ Qb,
    float* __restrict__ A)
{
    __shared__ float st[8][144];

    const int w  = threadIdx.x;
    const int i  = blockIdx.x % KK;
    const int bh = blockIdx.x / KK;
    const int h  = bh & 127;
    const int b  = bh >> 7;
    const int hr = clampi(h + 2 * i - 6, 0, HH - 1);

    const float* Krow = Kb + (size_t)b * CC * HWSZ + hr * WW;
    const float* Qpix = Qb + (size_t)b * CC * HWSZ + h * WW + w;

    float sc[KK];
#pragma unroll
    for (int j = 0; j < KK; ++j) sc[j] = 0.f;

    for (int c0 = 0; c0 < CC; c0 += 8) {
        __syncthreads();
#pragma unroll
        for (int cc = 0; cc < 8; ++cc) {
            const float* kr = Krow + (size_t)(c0 + cc) * HWSZ;
            for (int t = w; t < 140; t += 128)
                st[cc][t] = kr[clampi(t - 6, 0, WW - 1)];
        }
        __syncthreads();
#pragma unroll
        for (int cc = 0; cc < 8; ++cc) {
            const float qv = Qpix[(size_t)(c0 + cc) * HWSZ];
#pragma unroll
            for (int j = 0; j < KK; ++j)
                sc[j] = fmaf(st[cc][w + 2 * j], qv, sc[j]);
        }
    }

    float* Ap = A + ((size_t)(b * K2 + i * KK) * HH + h) * WW + w;
#pragma unroll
    for (int j = 0; j < KK; ++j) Ap[(size_t)j * HWSZ] = sc[j];
}

// ---------------------------------------------------------------------------
// K3: softmax over 49 (recomputed per pixel from complete A) + V-aggregate.
// Grid: (b,h,cg) = 1024 blocks x 128 thr; cg = 16 output channels.
// O[b,c,h,w] = sum_k P[k] * V[b,c,hn(i),wn(j)].
// ---------------------------------------------------------------------------
__global__ __launch_bounds__(128) void aggr_kernel(
    const float* __restrict__ Vb, const float* __restrict__ A,
    float* __restrict__ O)
{
    __shared__ float st[4][KK][144];

    const int w  = threadIdx.x;
    const int cg = blockIdx.x & 3;
    const int h  = (blockIdx.x >> 2) & 127;
    const int b  = blockIdx.x >> 9;

    // softmax over the 49 neighbors for this pixel
    float pr[K2];
    const float* Ap = A + ((size_t)b * K2 * HH + h) * WW + w;
#pragma unroll
    for (int k = 0; k < K2; ++k) pr[k] = Ap[(size_t)k * HWSZ];
    float m = pr[0];
#pragma unroll
    for (int k = 1; k < K2; ++k) m = fmaxf(m, pr[k]);
    float s = 0.f;
#pragma unroll
    for (int k = 0; k < K2; ++k) { pr[k] = __expf(pr[k] - m); s += pr[k]; }
    const float inv = 1.f / s;
#pragma unroll
    for (int k = 0; k < K2; ++k) pr[k] *= inv;

    int hn[KK];
#pragma unroll
    for (int i = 0; i < KK; ++i) hn[i] = clampi(h + 2 * i - 6, 0, HH - 1);

    const float* Vbase = Vb + (size_t)b * CC * HWSZ;
    float* Op = O + ((size_t)(b * CC + cg * 16) * HH + h) * WW + w;

    for (int c0 = 0; c0 < 16; c0 += 4) {
        __syncthreads();
#pragma unroll
        for (int cc = 0; cc < 4; ++cc) {
            const float* vch = Vbase + (size_t)(cg * 16 + c0 + cc) * HWSZ;
#pragma unroll
            for (int i = 0; i < KK; ++i) {
                const float* vr = vch + hn[i] * WW;
                for (int t = w; t < 140; t += 128)
                    st[cc][i][t] = vr[clampi(t - 6, 0, WW - 1)];
            }
        }
        __syncthreads();
#pragma unroll
        for (int cc = 0; cc < 4; ++cc) {
            float oc = 0.f;
#pragma unroll
            for (int i = 0; i < KK; ++i)
#pragma unroll
                for (int j = 0; j < KK; ++j)
                    oc = fmaf(st[cc][i][w + 2 * j], pr[i * KK + j], oc);
            Op[(size_t)(c0 + cc) * HWSZ] = oc;
        }
    }
}

// ---------------------------------------------------------------------------
// K4: out = Wt @ O + x. Grid: og(0..3) x 128 pixel-blocks, 256 thr.
// ---------------------------------------------------------------------------
__global__ __launch_bounds__(256) void wt_kernel(
    const float* __restrict__ O, const float* __restrict__ x,
    const float* __restrict__ Wt, float* __restrict__ out)
{
    const int pb = blockIdx.x & 127;
    const int og = blockIdx.x >> 7;            // 0..3
    const int p  = pb * 256 + threadIdx.x;
    const int b  = p >> 14;
    const int hw = p & 16383;
    const int o0 = og * 16;

    const float* Oq = O + (size_t)b * CC * HWSZ + hw;
    float fin[16];
#pragma unroll
    for (int i = 0; i < 16; ++i)
        fin[i] = x[((size_t)b * CC + o0 + i) * HWSZ + hw];

#pragma unroll 4
    for (int c = 0; c < CC; ++c) {
        const float ov = Oq[(size_t)c * HWSZ];
#pragma unroll
        for (int i = 0; i < 16; ++i)
            fin[i] = fmaf(Wt[(o0 + i) * CC + c], ov, fin[i]);
    }

#pragma unroll
    for (int i = 0; i < 16; ++i)
        out[((size_t)b * CC + o0 + i) * HWSZ + hw] = fin[i];
}

// ---------------------------------------------------------------------------
extern "C" void kernel_launch(void* const* d_in, const int* in_sizes, int n_in,
                              void* d_out, int out_size, void* d_ws, size_t ws_size,
                              hipStream_t stream)
{
    const float* x  = (const float*)d_in[0];
    const float* Wk = (const float*)d_in[1];
    const float* Wq = (const float*)d_in[2];
    const float* Wv = (const float*)d_in[3];
    const float* Wt = (const float*)d_in[4];
    float* out = (float*)d_out;

    const size_t tensor_elems = (size_t)BB * CC * HWSZ;  // 2,097,152
    float* Kb = (float*)d_ws;
    float* Qb = Kb + tensor_elems;
    float* Vb = Qb + tensor_elems;
    float* A  = Vb + tensor_elems;          // B*49*HW = 1,605,632 floats
    float* O  = Kb;                          // K dead after score_kernel

    hipLaunchKernelGGL(kqv_kernel, dim3(1024), dim3(256), 0, stream,
                       x, Wk, Wq, Wv, Kb, Qb, Vb);
    hipLaunchKernelGGL(score_kernel, dim3(BB * HH * KK), dim3(128), 0, stream,
                       Kb, Qb, A);
    hipLaunchKernelGGL(aggr_kernel, dim3(BB * HH * 4), dim3(128), 0, stream,
                       Vb, A, O);
    hipLaunchKernelGGL(wt_kernel, dim3(512), dim3(256), 0, stream,
                       O, x, Wt, out);
}

// Round 4
// 125.504 us; speedup vs baseline: 3.4038x; 1.1038x over previous
//
#include <hip/hip_runtime.h>

#define HH 128
#define WW 128
#define HWSZ (HH * WW)   // 16384
#define CC 64
#define BB 2
#define KK 7
#define K2 49

__device__ __forceinline__ int clampi(int v, int lo, int hi) {
    return v < lo ? lo : (v > hi ? hi : v);
}

// ---------------------------------------------------------------------------
// K1: K/Q/V = relu(W @ x). Grid: og(0..7) x 128 pixel-blocks, 256 thr.
// Each thread: 1 pixel, 8 output channels per matrix (24 accumulators).
// ---------------------------------------------------------------------------
__global__ __launch_bounds__(256) void kqv_kernel(
    const float* __restrict__ x,  const float* __restrict__ Wk,
    const float* __restrict__ Wq, const float* __restrict__ Wv,
    float* __restrict__ Ko, float* __restrict__ Qo, float* __restrict__ Vo)
{
    const int pb = blockIdx.x & 127;
    const int og = blockIdx.x >> 7;            // 0..7
    const int p  = pb * 256 + threadIdx.x;     // 0..32767
    const int b  = p >> 14;
    const int hw = p & 16383;
    const int o0 = og * 8;
    const float* xp = x + (size_t)b * CC * HWSZ + hw;

    float aK[8], aQ[8], aV[8];
#pragma unroll
    for (int i = 0; i < 8; ++i) { aK[i] = 0.f; aQ[i] = 0.f; aV[i] = 0.f; }

#pragma unroll 4
    for (int c = 0; c < CC; ++c) {
        const float xv = xp[(size_t)c * HWSZ];
#pragma unroll
        for (int i = 0; i < 8; ++i) {
            aK[i] = fmaf(Wk[(o0 + i) * CC + c], xv, aK[i]);
            aQ[i] = fmaf(Wq[(o0 + i) * CC + c], xv, aQ[i]);
            aV[i] = fmaf(Wv[(o0 + i) * CC + c], xv, aV[i]);
        }
    }

    const size_t obase = (size_t)b * CC * HWSZ + (size_t)o0 * HWSZ + hw;
#pragma unroll
    for (int i = 0; i < 8; ++i) {
        Ko[obase + (size_t)i * HWSZ] = fmaxf(aK[i], 0.f);
        Qo[obase + (size_t)i * HWSZ] = fmaxf(aQ[i], 0.f);
        Vo[obase + (size_t)i * HWSZ] = fmaxf(aV[i], 0.f);
    }
}

// ---------------------------------------------------------------------------
// K2: scores A[b][k=i*7+j][h][w] = sum_c K[b,c,hn(i),wn(j)] * Q[b,c,h,w].
// Grid: (b,h,i) = 1792 blocks x 256 thr (4 waves). In-block channel split:
// half ch=0 reduces c 0..31, half ch=1 reduces c 32..63; LDS-reduce at end.
// 28 waves/CU, no redundant staging, no extra global buffers.
// ---------------------------------------------------------------------------
__global__ __launch_bounds__(256) void score_kernel(
    const float* __restrict__ Kb, const float* __restrict__ Qb,
    float* __restrict__ A)
{
    __shared__ float st[2][8][144];
    __shared__ float red[KK][128];

    const int w  = threadIdx.x & 127;
    const int ch = threadIdx.x >> 7;           // 0/1: channel half
    const int i  = blockIdx.x % KK;
    const int bh = blockIdx.x / KK;
    const int h  = bh & 127;
    const int b  = bh >> 7;
    const int hr = clampi(h + 2 * i - 6, 0, HH - 1);

    const float* Krow = Kb + (size_t)b * CC * HWSZ + hr * WW;
    const float* Qpix = Qb + (size_t)b * CC * HWSZ + h * WW + w;

    float sc[KK];
#pragma unroll
    for (int j = 0; j < KK; ++j) sc[j] = 0.f;

    const int cbase = ch * 32;
    for (int c0 = cbase; c0 < cbase + 32; c0 += 8) {
        __syncthreads();
#pragma unroll
        for (int cc = 0; cc < 8; ++cc) {
            const float* kr = Krow + (size_t)(c0 + cc) * HWSZ;
            for (int t = w; t < 140; t += 128)
                st[ch][cc][t] = kr[clampi(t - 6, 0, WW - 1)];
        }
        __syncthreads();
#pragma unroll
        for (int cc = 0; cc < 8; ++cc) {
            const float qv = Qpix[(size_t)(c0 + cc) * HWSZ];
#pragma unroll
            for (int j = 0; j < KK; ++j)
                sc[j] = fmaf(st[ch][cc][w + 2 * j], qv, sc[j]);
        }
    }

    // cross-half reduction
    if (ch == 1) {
#pragma unroll
        for (int j = 0; j < KK; ++j) red[j][w] = sc[j];
    }
    __syncthreads();
    if (ch == 0) {
        float* Ap = A + ((size_t)(b * K2 + i * KK) * HH + h) * WW + w;
#pragma unroll
        for (int j = 0; j < KK; ++j)
            Ap[(size_t)j * HWSZ] = sc[j] + red[j][w];
    }
}

// ---------------------------------------------------------------------------
// K2.5: softmax over k2=49, in place on A. One thread per pixel; each thread
// reads and rewrites only its own 49 values -> race-free, deterministic.
// ---------------------------------------------------------------------------
__global__ __launch_bounds__(256) void softmax_kernel(float* __restrict__ A)
{
    const int p  = blockIdx.x * 256 + threadIdx.x;  // 0..32767
    const int b  = p >> 14;
    const int hw = p & 16383;
    float* Ap = A + (size_t)b * K2 * HWSZ + hw;

    float pr[K2];
#pragma unroll
    for (int k = 0; k < K2; ++k) pr[k] = Ap[(size_t)k * HWSZ];
    float m = pr[0];
#pragma unroll
    for (int k = 1; k < K2; ++k) m = fmaxf(m, pr[k]);
    float s = 0.f;
#pragma unroll
    for (int k = 0; k < K2; ++k) { pr[k] = __expf(pr[k] - m); s += pr[k]; }
    const float inv = 1.f / s;
#pragma unroll
    for (int k = 0; k < K2; ++k) Ap[(size_t)k * HWSZ] = pr[k] * inv;
}

// ---------------------------------------------------------------------------
// K3: V-aggregate with precomputed probabilities P (=A after softmax).
// Grid: (b,h,cg) = 2048 blocks x 128 thr; cg = 8 output channels.
// ---------------------------------------------------------------------------
__global__ __launch_bounds__(128) void aggr_kernel(
    const float* __restrict__ Vb, const float* __restrict__ P,
    float* __restrict__ O)
{
    __shared__ float st[4][KK][144];

    const int w  = threadIdx.x;
    const int cg = blockIdx.x & 7;
    const int h  = (blockIdx.x >> 3) & 127;
    const int b  = blockIdx.x >> 10;

    float pr[K2];
    const float* Pp = P + ((size_t)b * K2 * HH + h) * WW + w;
#pragma unroll
    for (int k = 0; k < K2; ++k) pr[k] = Pp[(size_t)k * HWSZ];

    int hn[KK];
#pragma unroll
    for (int i = 0; i < KK; ++i) hn[i] = clampi(h + 2 * i - 6, 0, HH - 1);

    const float* Vbase = Vb + (size_t)b * CC * HWSZ;
    float* Op = O + ((size_t)(b * CC + cg * 8) * HH + h) * WW + w;

    for (int c0 = 0; c0 < 8; c0 += 4) {
        __syncthreads();
#pragma unroll
        for (int cc = 0; cc < 4; ++cc) {
            const float* vch = Vbase + (size_t)(cg * 8 + c0 + cc) * HWSZ;
#pragma unroll
            for (int i = 0; i < KK; ++i) {
                const float* vr = vch + hn[i] * WW;
                for (int t = w; t < 140; t += 128)
                    st[cc][i][t] = vr[clampi(t - 6, 0, WW - 1)];
            }
        }
        __syncthreads();
#pragma unroll
        for (int cc = 0; cc < 4; ++cc) {
            float oc = 0.f;
#pragma unroll
            for (int i = 0; i < KK; ++i)
#pragma unroll
                for (int j = 0; j < KK; ++j)
                    oc = fmaf(st[cc][i][w + 2 * j], pr[i * KK + j], oc);
            Op[(size_t)(c0 + cc) * HWSZ] = oc;
        }
    }
}

// ---------------------------------------------------------------------------
// K4: out = Wt @ O + x. Grid: og(0..7) x 128 pixel-blocks, 256 thr.
// ---------------------------------------------------------------------------
__global__ __launch_bounds__(256) void wt_kernel(
    const float* __restrict__ O, const float* __restrict__ x,
    const float* __restrict__ Wt, float* __restrict__ out)
{
    const int pb = blockIdx.x & 127;
    const int og = blockIdx.x >> 7;            // 0..7
    const int p  = pb * 256 + threadIdx.x;
    const int b  = p >> 14;
    const int hw = p & 16383;
    const int o0 = og * 8;

    const float* Oq = O + (size_t)b * CC * HWSZ + hw;
    float fin[8];
#pragma unroll
    for (int i = 0; i < 8; ++i)
        fin[i] = x[((size_t)b * CC + o0 + i) * HWSZ + hw];

#pragma unroll 4
    for (int c = 0; c < CC; ++c) {
        const float ov = Oq[(size_t)c * HWSZ];
#pragma unroll
        for (int i = 0; i < 8; ++i)
            fin[i] = fmaf(Wt[(o0 + i) * CC + c], ov, fin[i]);
    }

#pragma unroll
    for (int i = 0; i < 8; ++i)
        out[((size_t)b * CC + o0 + i) * HWSZ + hw] = fin[i];
}

// ---------------------------------------------------------------------------
extern "C" void kernel_launch(void* const* d_in, const int* in_sizes, int n_in,
                              void* d_out, int out_size, void* d_ws, size_t ws_size,
                              hipStream_t stream)
{
    const float* x  = (const float*)d_in[0];
    const float* Wk = (const float*)d_in[1];
    const float* Wq = (const float*)d_in[2];
    const float* Wv = (const float*)d_in[3];
    const float* Wt = (const float*)d_in[4];
    float* out = (float*)d_out;

    const size_t tensor_elems = (size_t)BB * CC * HWSZ;  // 2,097,152
    float* Kb = (float*)d_ws;
    float* Qb = Kb + tensor_elems;
    float* Vb = Qb + tensor_elems;
    float* A  = Vb + tensor_elems;          // B*49*HW = 1,605,632 floats
    float* O  = Kb;                          // K dead after score_kernel

    hipLaunchKernelGGL(kqv_kernel, dim3(1024), dim3(256), 0, stream,
                       x, Wk, Wq, Wv, Kb, Qb, Vb);
    hipLaunchKernelGGL(score_kernel, dim3(BB * HH * KK), dim3(256), 0, stream,
                       Kb, Qb, A);
    hipLaunchKernelGGL(softmax_kernel, dim3(BB * HWSZ / 256), dim3(256), 0, stream,
                       A);
    hipLaunchKernelGGL(aggr_kernel, dim3(BB * HH * 8), dim3(128), 0, stream,
                       Vb, A, O);
    hipLaunchKernelGGL(wt_kernel, dim3(1024), dim3(256), 0, stream,
                       O, x, Wt, out);
}

// Round 5
// 119.880 us; speedup vs baseline: 3.5635x; 1.0469x over previous
//
#include <hip/hip_runtime.h>

#define HH 128
#define WW 128
#define HWSZ (HH * WW)   // 16384
#define CC 64
#define BB 2
#define KK 7
#define K2 49
#define PSTRIDE 52       // padded k2 stride for At/Pt (13 float4)

__device__ __forceinline__ int clampi(int v, int lo, int hi) {
    return v < lo ? lo : (v > hi ? hi : v);
}

// ---------------------------------------------------------------------------
// K1: K/Q/V = relu(W @ x). Grid 1024 = xcd(8) x [pb16 x og8]. XCD x owns
// pixel rows h in [32x..32x+32) (both batches stacked), so K/Q/V rows it
// writes stay in its L2 for score/aggr. Q written transposed Qt[p][64].
// ---------------------------------------------------------------------------
__global__ __launch_bounds__(256) void kqv_kernel(
    const float* __restrict__ x,  const float* __restrict__ Wk,
    const float* __restrict__ Wq, const float* __restrict__ Wv,
    float* __restrict__ Ko, float* __restrict__ Qt, float* __restrict__ Vo)
{
    const int xcd = blockIdx.x & 7;
    const int s   = blockIdx.x >> 3;          // 0..127
    const int pb  = xcd * 16 + (s & 15);      // 0..127
    const int og  = s >> 4;                   // 0..7
    const int p   = pb * 256 + threadIdx.x;   // 0..32767
    const int b   = p >> 14;
    const int hw  = p & 16383;
    const int o0  = og * 8;
    const float* xp = x + (size_t)b * CC * HWSZ + hw;

    float aK[8], aQ[8], aV[8];
#pragma unroll
    for (int i = 0; i < 8; ++i) { aK[i] = 0.f; aQ[i] = 0.f; aV[i] = 0.f; }

#pragma unroll 4
    for (int c = 0; c < CC; ++c) {
        const float xv = xp[(size_t)c * HWSZ];
#pragma unroll
        for (int i = 0; i < 8; ++i) {
            aK[i] = fmaf(Wk[(o0 + i) * CC + c], xv, aK[i]);
            aQ[i] = fmaf(Wq[(o0 + i) * CC + c], xv, aQ[i]);
            aV[i] = fmaf(Wv[(o0 + i) * CC + c], xv, aV[i]);
        }
    }

    const size_t obase = (size_t)b * CC * HWSZ + (size_t)o0 * HWSZ + hw;
#pragma unroll
    for (int i = 0; i < 8; ++i) {
        Ko[obase + (size_t)i * HWSZ] = fmaxf(aK[i], 0.f);
        Vo[obase + (size_t)i * HWSZ] = fmaxf(aV[i], 0.f);
    }
    float4* qtv = (float4*)(Qt + (size_t)p * CC + o0);
    qtv[0] = make_float4(fmaxf(aQ[0], 0.f), fmaxf(aQ[1], 0.f),
                         fmaxf(aQ[2], 0.f), fmaxf(aQ[3], 0.f));
    qtv[1] = make_float4(fmaxf(aQ[4], 0.f), fmaxf(aQ[5], 0.f),
                         fmaxf(aQ[6], 0.f), fmaxf(aQ[7], 0.f));
}

// ---------------------------------------------------------------------------
// K2: scores At[p][i*7+j] = sum_c K[b,c,hn(i),wn(j)] * Q[b,c,h,w].
// Grid 1792 = xcd(8) x [bh32 x i7]; all (h,i) blocks sharing K rows land on
// one XCD -> L2-resident rows. 256 thr = 128 w x 2 channel-halves.
// ---------------------------------------------------------------------------
__global__ __launch_bounds__(256) void score_kernel(
    const float* __restrict__ Kb, const float* __restrict__ Qt,
    float* __restrict__ At)
{
    __shared__ float st[16][144];
    __shared__ float red[KK][128];

    const int xcd = blockIdx.x & 7;
    const int s   = blockIdx.x >> 3;        // 0..223
    const int bh  = xcd * 32 + s / 7;       // 0..255
    const int i   = s % 7;
    const int w   = threadIdx.x & 127;
    const int ch  = threadIdx.x >> 7;       // channel half
    const int h   = bh & 127;
    const int b   = bh >> 7;
    const int hr  = clampi(h + 2 * i - 6, 0, HH - 1);
    const int p   = b * HWSZ + h * WW + w;

    const float* Qp    = Qt + (size_t)p * CC + ch * 32;
    const float* Kbase = Kb + (size_t)b * CC * HWSZ + hr * WW;

    float sc[KK];
#pragma unroll
    for (int j = 0; j < KK; ++j) sc[j] = 0.f;

    for (int c0 = 0; c0 < 32; c0 += 8) {
        __syncthreads();
#pragma unroll
        for (int rr = 0; rr < 8; ++rr) {
            const float* kr = Kbase + (size_t)(ch * 32 + c0 + rr) * HWSZ;
            for (int t = w; t < 140; t += 128)
                st[ch * 8 + rr][t] = kr[clampi(t - 6, 0, WW - 1)];
        }
        __syncthreads();
        const float4 q0 = *(const float4*)(Qp + c0);
        const float4 q1 = *(const float4*)(Qp + c0 + 4);
        const float qs[8] = {q0.x, q0.y, q0.z, q0.w, q1.x, q1.y, q1.z, q1.w};
#pragma unroll
        for (int rr = 0; rr < 8; ++rr)
#pragma unroll
            for (int j = 0; j < KK; ++j)
                sc[j] = fmaf(st[ch * 8 + rr][w + 2 * j], qs[rr], sc[j]);
    }

    if (ch == 1) {
#pragma unroll
        for (int j = 0; j < KK; ++j) red[j][w] = sc[j];
    }
    __syncthreads();
    if (ch == 0) {
        float* Ap = At + (size_t)p * PSTRIDE + i * KK;
#pragma unroll
        for (int j = 0; j < KK; ++j) Ap[j] = sc[j] + red[j][w];
    }
}

// ---------------------------------------------------------------------------
// K2.5: softmax over 49, in place on At (vector reads: 12 float4 + 1).
// Grid 128 = xcd(8) x 16; pixels match the XCD that wrote them.
// ---------------------------------------------------------------------------
__global__ __launch_bounds__(256) void softmax_kernel(float* __restrict__ At)
{
    const int xcd = blockIdx.x & 7;
    const int s   = blockIdx.x >> 3;        // 0..15
    const int p   = xcd * 4096 + s * 256 + threadIdx.x;
    float* Ap = At + (size_t)p * PSTRIDE;

    float pr[52];
#pragma unroll
    for (int t = 0; t < 12; ++t) ((float4*)pr)[t] = ((const float4*)Ap)[t];
    pr[48] = Ap[48];

    float m = pr[0];
#pragma unroll
    for (int k = 1; k < K2; ++k) m = fmaxf(m, pr[k]);
    float sum = 0.f;
#pragma unroll
    for (int k = 0; k < K2; ++k) { pr[k] = __expf(pr[k] - m); sum += pr[k]; }
    const float inv = 1.f / sum;
#pragma unroll
    for (int k = 0; k < K2; ++k) pr[k] *= inv;

#pragma unroll
    for (int t = 0; t < 12; ++t) ((float4*)Ap)[t] = ((const float4*)pr)[t];
    Ap[48] = pr[48];
}

// ---------------------------------------------------------------------------
// K3: V-aggregate, no LDS, no syncs. Grid 2048 = xcd(8) x [bh32 x cg8];
// 256 thr = 128 w x 2 ch-subgroups (4 channels each). V rows read direct
// from global (L1/L2-resident after swizzle); P via 13 float4.
// Output written transposed Ot[p][64] (one float4 per thread).
// ---------------------------------------------------------------------------
__global__ __launch_bounds__(256) void aggr_kernel(
    const float* __restrict__ Vb, const float* __restrict__ Pt,
    float* __restrict__ Ot)
{
    const int xcd = blockIdx.x & 7;
    const int s   = blockIdx.x >> 3;        // 0..255
    const int bh  = xcd * 32 + (s >> 3);
    const int cg  = s & 7;
    const int w   = threadIdx.x & 127;
    const int cs  = threadIdx.x >> 7;
    const int h   = bh & 127;
    const int b   = bh >> 7;
    const int p   = b * HWSZ + h * WW + w;

    float pr[52];
    const float4* Pv = (const float4*)(Pt + (size_t)p * PSTRIDE);
#pragma unroll
    for (int t = 0; t < 12; ++t) ((float4*)pr)[t] = Pv[t];
    pr[48] = Pt[(size_t)p * PSTRIDE + 48];

    int hn[KK], wn[KK];
#pragma unroll
    for (int i = 0; i < KK; ++i) hn[i] = clampi(h + 2 * i - 6, 0, HH - 1);
#pragma unroll
    for (int j = 0; j < KK; ++j) wn[j] = clampi(w + 2 * j - 6, 0, WW - 1);

    const int c0 = cg * 8 + cs * 4;
    float acc[4] = {0.f, 0.f, 0.f, 0.f};
#pragma unroll
    for (int cc = 0; cc < 4; ++cc) {
        const float* vch = Vb + (size_t)(b * CC + c0 + cc) * HWSZ;
#pragma unroll
        for (int i = 0; i < KK; ++i) {
            const float* vr = vch + hn[i] * WW;
#pragma unroll
            for (int j = 0; j < KK; ++j)
                acc[cc] = fmaf(vr[wn[j]], pr[i * KK + j], acc[cc]);
        }
    }
    *(float4*)(Ot + (size_t)p * CC + c0) =
        make_float4(acc[0], acc[1], acc[2], acc[3]);
}

// ---------------------------------------------------------------------------
// K4: out = Wt @ O + x. Grid 1024 = xcd(8) x [pb16 x og8]; O read as
// 16 float4 per thread from Ot; weights wave-uniform (scalar loads).
// ---------------------------------------------------------------------------
__global__ __launch_bounds__(256) void wt_kernel(
    const float* __restrict__ Ot, const float* __restrict__ x,
    const float* __restrict__ Wt, float* __restrict__ out)
{
    const int xcd = blockIdx.x & 7;
    const int s   = blockIdx.x >> 3;        // 0..127
    const int pb  = xcd * 16 + (s & 15);
    const int og  = s >> 4;
    const int p   = pb * 256 + threadIdx.x;
    const int b   = p >> 14;
    const int hw  = p & 16383;
    const int o0  = og * 8;

    float fin[8];
#pragma unroll
    for (int i = 0; i < 8; ++i)
        fin[i] = x[((size_t)b * CC + o0 + i) * HWSZ + hw];

    const float4* ov = (const float4*)(Ot + (size_t)p * CC);
#pragma unroll
    for (int c4 = 0; c4 < 16; ++c4) {
        const float4 o4 = ov[c4];
        const float oc[4] = {o4.x, o4.y, o4.z, o4.w};
#pragma unroll
        for (int cc = 0; cc < 4; ++cc) {
            const int c = c4 * 4 + cc;
#pragma unroll
            for (int i = 0; i < 8; ++i)
                fin[i] = fmaf(Wt[(o0 + i) * CC + c], oc[cc], fin[i]);
        }
    }

#pragma unroll
    for (int i = 0; i < 8; ++i)
        out[((size_t)b * CC + o0 + i) * HWSZ + hw] = fin[i];
}

// ---------------------------------------------------------------------------
extern "C" void kernel_launch(void* const* d_in, const int* in_sizes, int n_in,
                              void* d_out, int out_size, void* d_ws, size_t ws_size,
                              hipStream_t stream)
{
    const float* x  = (const float*)d_in[0];
    const float* Wk = (const float*)d_in[1];
    const float* Wq = (const float*)d_in[2];
    const float* Wv = (const float*)d_in[3];
    const float* Wt = (const float*)d_in[4];
    float* out = (float*)d_out;

    const size_t T = (size_t)BB * CC * HWSZ;      // 2,097,152 floats
    float* Kb = (float*)d_ws;
    float* Qt = Kb + T;
    float* Vb = Qt + T;
    float* At = Vb + T;                            // BB*HWSZ*52 = 1,703,936
    float* Ot = Kb;                                // Kb dead after score

    hipLaunchKernelGGL(kqv_kernel, dim3(1024), dim3(256), 0, stream,
                       x, Wk, Wq, Wv, Kb, Qt, Vb);
    hipLaunchKernelGGL(score_kernel, dim3(BB * HH * KK), dim3(256), 0, stream,
                       Kb, Qt, At);
    hipLaunchKernelGGL(softmax_kernel, dim3(128), dim3(256), 0, stream, At);
    hipLaunchKernelGGL(aggr_kernel, dim3(2048), dim3(256), 0, stream,
                       Vb, At, Ot);
    hipLaunchKernelGGL(wt_kernel, dim3(1024), dim3(256), 0, stream,
                       Ot, x, Wt, out);
}

// Round 6
// 98.818 us; speedup vs baseline: 4.3230x; 1.2131x over previous
//
#include <hip/hip_runtime.h>

#define HH 128
#define WW 128
#define HWSZ (HH * WW)   // 16384
#define CC 64
#define BB 2
#define KK 7
#define K2 49
#define PSTRIDE 52       // padded k2 stride for At (13 float4, 16B-aligned rows)
#define PADROW 140       // [3 pad][64 even][3 pad][3 pad][64 odd][3 pad]
#define EV_OFF 3
#define OD_OFF 73

__device__ __forceinline__ int clampi(int v, int lo, int hi) {
    return v < lo ? lo : (v > hi ? hi : v);
}

// unaligned-safe 16B load (global_load_dwordx4 needs only 4B alignment)
__device__ __forceinline__ void ld4u(float* dst, const float* src) {
    __builtin_memcpy(dst, src, 16);
}

// ---------------------------------------------------------------------------
// K1: K/Q/V = relu(W @ x). Grid 1024 = xcd(8) x [pb16 x og8].
// K,V written parity-split+padded (PADROW): lane w -> slot (w&1?73:3)+(w>>1);
// w==0 / w==127 lanes also fill the replicate-pad slots of both planes.
// Q written transposed Qt[p][64] into d_out (dead before wt writes out).
// ---------------------------------------------------------------------------
__global__ __launch_bounds__(256) void kqv_kernel(
    const float* __restrict__ x,  const float* __restrict__ Wk,
    const float* __restrict__ Wq, const float* __restrict__ Wv,
    float* __restrict__ Kp, float* __restrict__ Qt, float* __restrict__ Vp)
{
    const int xcd = blockIdx.x & 7;
    const int s   = blockIdx.x >> 3;          // 0..127
    const int pb  = xcd * 16 + (s & 15);      // 0..127
    const int og  = s >> 4;                   // 0..7
    const int p   = pb * 256 + threadIdx.x;   // 0..32767
    const int b   = p >> 14;
    const int hw  = p & 16383;
    const int h   = hw >> 7;
    const int w   = hw & 127;
    const int o0  = og * 8;
    const float* xp = x + (size_t)b * CC * HWSZ + hw;

    float aK[8], aQ[8], aV[8];
#pragma unroll
    for (int i = 0; i < 8; ++i) { aK[i] = 0.f; aQ[i] = 0.f; aV[i] = 0.f; }

#pragma unroll 4
    for (int c = 0; c < CC; ++c) {
        const float xv = xp[(size_t)c * HWSZ];
#pragma unroll
        for (int i = 0; i < 8; ++i) {
            aK[i] = fmaf(Wk[(o0 + i) * CC + c], xv, aK[i]);
            aQ[i] = fmaf(Wq[(o0 + i) * CC + c], xv, aQ[i]);
            aV[i] = fmaf(Wv[(o0 + i) * CC + c], xv, aV[i]);
        }
    }

    const int slot = ((w & 1) ? OD_OFF : EV_OFF) + (w >> 1);
#pragma unroll
    for (int i = 0; i < 8; ++i) {
        const float kv = fmaxf(aK[i], 0.f);
        const float vv = fmaxf(aV[i], 0.f);
        float* krow = Kp + ((size_t)(b * CC + o0 + i) * HH + h) * PADROW;
        float* vrow = Vp + ((size_t)(b * CC + o0 + i) * HH + h) * PADROW;
        krow[slot] = kv;
        vrow[slot] = vv;
        if (w == 0) {        // replicate-pad: pos<0 clamps to K[0]
#pragma unroll
            for (int t = 0; t < 3; ++t) {
                krow[t] = kv; krow[70 + t] = kv;
                vrow[t] = vv; vrow[70 + t] = vv;
            }
        }
        if (w == 127) {      // pos>127 clamps to K[127]
#pragma unroll
            for (int t = 0; t < 3; ++t) {
                krow[67 + t] = kv; krow[137 + t] = kv;
                vrow[67 + t] = vv; vrow[137 + t] = vv;
            }
        }
    }

    float4* qtv = (float4*)(Qt + (size_t)p * CC + o0);
    qtv[0] = make_float4(fmaxf(aQ[0], 0.f), fmaxf(aQ[1], 0.f),
                         fmaxf(aQ[2], 0.f), fmaxf(aQ[3], 0.f));
    qtv[1] = make_float4(fmaxf(aQ[4], 0.f), fmaxf(aQ[5], 0.f),
                         fmaxf(aQ[6], 0.f), fmaxf(aQ[7], 0.f));
}

// ---------------------------------------------------------------------------
// K2: scores At[p][i*7+j] = sum_c K[c][hr(i)][w+2j-6] * Q[p][c].
// Grid 1792 = xcd(8) x [bh32 x i7], 128 thr, NO LDS, NO barriers.
// Lane w's 7 dilated neighbors = 7 consecutive floats in its parity plane
// -> two unaligned dwordx4 loads per channel. Pads absorb the edge clamps.
// ---------------------------------------------------------------------------
__global__ __launch_bounds__(128) void score_kernel(
    const float* __restrict__ Kp, const float* __restrict__ Qt,
    float* __restrict__ At)
{
    const int xcd = blockIdx.x & 7;
    const int s   = blockIdx.x >> 3;        // 0..223
    const int bh  = xcd * 32 + s / 7;       // 0..255
    const int i   = s % 7;
    const int w   = threadIdx.x;            // 0..127
    const int h   = bh & 127;
    const int b   = bh >> 7;
    const int hr  = clampi(h + 2 * i - 6, 0, HH - 1);
    const int p   = b * HWSZ + h * WW + w;

    const float* Qp = Qt + (size_t)p * CC;
    const float* Kbase = Kp + ((size_t)(b * CC) * HH + hr) * PADROW
                         + ((w & 1) ? OD_OFF : EV_OFF) + ((w >> 1) - 3);
    const size_t cstride = (size_t)HH * PADROW;

    float sc[KK];
#pragma unroll
    for (int j = 0; j < KK; ++j) sc[j] = 0.f;

    for (int c4 = 0; c4 < CC; c4 += 4) {
        const float4 q4 = *(const float4*)(Qp + c4);
        const float qv[4] = {q4.x, q4.y, q4.z, q4.w};
#pragma unroll
        for (int cc = 0; cc < 4; ++cc) {
            const float* row = Kbase + (size_t)(c4 + cc) * cstride;
            float kv[8];
            ld4u(kv, row);
            ld4u(kv + 4, row + 4);
#pragma unroll
            for (int j = 0; j < KK; ++j)
                sc[j] = fmaf(kv[j], qv[cc], sc[j]);
        }
    }

    float* Ap = At + (size_t)p * PSTRIDE + i * KK;
#pragma unroll
    for (int j = 0; j < KK; ++j) Ap[j] = sc[j];
}

// ---------------------------------------------------------------------------
// K3: fused softmax(49) + V-aggregate. Grid 2048 = xcd(8) x [bh32 x cg8],
// 256 thr = 128 w x 2 cs (4 channels each). Softmax recomputed per block
// (identical op order per pixel -> deterministic). NO LDS, NO barriers.
// V read via the same parity-plane dwordx4 trick. Ot[p][64] f4 store.
// ---------------------------------------------------------------------------
__global__ __launch_bounds__(256) void aggr_kernel(
    const float* __restrict__ Vp, const float* __restrict__ At,
    float* __restrict__ Ot)
{
    const int xcd = blockIdx.x & 7;
    const int s   = blockIdx.x >> 3;        // 0..255
    const int bh  = xcd * 32 + (s >> 3);
    const int cg  = s & 7;
    const int w   = threadIdx.x & 127;
    const int cs  = threadIdx.x >> 7;
    const int h   = bh & 127;
    const int b   = bh >> 7;
    const int p   = b * HWSZ + h * WW + w;

    float pr[52];
    const float4* Av = (const float4*)(At + (size_t)p * PSTRIDE);
#pragma unroll
    for (int t = 0; t < 13; ++t) ((float4*)pr)[t] = Av[t];

    float m = pr[0];
#pragma unroll
    for (int k = 1; k < K2; ++k) m = fmaxf(m, pr[k]);
    float sum = 0.f;
#pragma unroll
    for (int k = 0; k < K2; ++k) { pr[k] = __expf(pr[k] - m); sum += pr[k]; }
    const float inv = 1.f / sum;
#pragma unroll
    for (int k = 0; k < K2; ++k) pr[k] *= inv;

    int hn[KK];
#pragma unroll
    for (int i = 0; i < KK; ++i) hn[i] = clampi(h + 2 * i - 6, 0, HH - 1);

    const int poff  = ((w & 1) ? OD_OFF : EV_OFF) + ((w >> 1) - 3);
    const int c0    = cg * 8 + cs * 4;
    float acc[4] = {0.f, 0.f, 0.f, 0.f};
#pragma unroll
    for (int cc = 0; cc < 4; ++cc) {
        const float* vch = Vp + (size_t)(b * CC + c0 + cc) * HH * PADROW;
#pragma unroll
        for (int i = 0; i < KK; ++i) {
            const float* row = vch + (size_t)hn[i] * PADROW + poff;
            float vv[8];
            ld4u(vv, row);
            ld4u(vv + 4, row + 4);
#pragma unroll
            for (int j = 0; j < KK; ++j)
                acc[cc] = fmaf(vv[j], pr[i * KK + j], acc[cc]);
        }
    }
    *(float4*)(Ot + (size_t)p * CC + c0) =
        make_float4(acc[0], acc[1], acc[2], acc[3]);
}

// ---------------------------------------------------------------------------
// K4: out = Wt @ O + x. Grid 1024 = xcd(8) x [pb16 x og8].
// ---------------------------------------------------------------------------
__global__ __launch_bounds__(256) void wt_kernel(
    const float* __restrict__ Ot, const float* __restrict__ x,
    const float* __restrict__ Wt, float* __restrict__ out)
{
    const int xcd = blockIdx.x & 7;
    const int s   = blockIdx.x >> 3;        // 0..127
    const int pb  = xcd * 16 + (s & 15);
    const int og  = s >> 4;
    const int p   = pb * 256 + threadIdx.x;
    const int b   = p >> 14;
    const int hw  = p & 16383;
    const int o0  = og * 8;

    float fin[8];
#pragma unroll
    for (int i = 0; i < 8; ++i)
        fin[i] = x[((size_t)b * CC + o0 + i) * HWSZ + hw];

    const float4* ov = (const float4*)(Ot + (size_t)p * CC);
#pragma unroll
    for (int c4 = 0; c4 < 16; ++c4) {
        const float4 o4 = ov[c4];
        const float oc[4] = {o4.x, o4.y, o4.z, o4.w};
#pragma unroll
        for (int cc = 0; cc < 4; ++cc) {
            const int c = c4 * 4 + cc;
#pragma unroll
            for (int i = 0; i < 8; ++i)
                fin[i] = fmaf(Wt[(o0 + i) * CC + c], oc[cc], fin[i]);
        }
    }

#pragma unroll
    for (int i = 0; i < 8; ++i)
        out[((size_t)b * CC + o0 + i) * HWSZ + hw] = fin[i];
}

// ---------------------------------------------------------------------------
extern "C" void kernel_launch(void* const* d_in, const int* in_sizes, int n_in,
                              void* d_out, int out_size, void* d_ws, size_t ws_size,
                              hipStream_t stream)
{
    const float* x  = (const float*)d_in[0];
    const float* Wk = (const float*)d_in[1];
    const float* Wq = (const float*)d_in[2];
    const float* Wv = (const float*)d_in[3];
    const float* Wt = (const float*)d_in[4];
    float* out = (float*)d_out;

    const size_t KP_ELEMS = (size_t)BB * CC * HH * PADROW;  // 2,293,760
    float* Kp = (float*)d_ws;
    float* Vp = Kp + KP_ELEMS;
    float* At = Vp + KP_ELEMS;       // BB*HWSZ*52 = 1,703,936 -> 25.2 MB total
    float* Qt = out;                 // d_out as scratch; dead before wt writes
    float* Ot = Kp;                  // Kp dead after score

    hipLaunchKernelGGL(kqv_kernel, dim3(1024), dim3(256), 0, stream,
                       x, Wk, Wq, Wv, Kp, Qt, Vp);
    hipLaunchKernelGGL(score_kernel, dim3(BB * HH * KK), dim3(128), 0, stream,
                       Kp, Qt, At);
    hipLaunchKernelGGL(aggr_kernel, dim3(2048), dim3(256), 0, stream,
                       Vp, At, Ot);
    hipLaunchKernelGGL(wt_kernel, dim3(1024), dim3(256), 0, stream,
                       Ot, x, Wt, out);
}